// Round 5
// baseline (7045.435 us; speedup 1.0000x reference)
//
#include <hip/hip_runtime.h>

#define SEQL   512
#define HID    2048
#define NCLS   10

typedef _Float16 f16x8 __attribute__((ext_vector_type(8)));
typedef _Float16 f16x4 __attribute__((ext_vector_type(4)));
typedef float    f32x4 __attribute__((ext_vector_type(4)));
typedef unsigned uintx4 __attribute__((ext_vector_type(4)));

__device__ __forceinline__ float fast_tanh(float v) {
    float e = __expf(2.0f * v);
    return 1.0f - 2.0f / (e + 1.0f);
}

// whh fp32 -> fp16 (row-major [j][k] preserved)
__global__ void convert_w_kernel(const float* __restrict__ w, _Float16* __restrict__ o) {
    const int i = (blockIdx.x * 256 + threadIdx.x) * 4;
    const float4 v = *(const float4*)(w + i);
    f16x4 h;
    h[0] = (_Float16)v.x; h[1] = (_Float16)v.y;
    h[2] = (_Float16)v.z; h[3] = (_Float16)v.w;
    *(f16x4*)(o + i) = h;
}

// XCD-local 32-WG barrier — ROUND-2 PROVEN ENCODING (do not hand-roll cache bits):
//   arrive: workgroup-scope atomicAdd (executes at local L2)
//   spin:   agent-scope relaxed load (bypasses L1)
//   acquire: buffer_inv sc0 (invalidate this CU's L1; L2 untouched)
__device__ __forceinline__ void group_barrier(unsigned* gctr, unsigned bi) {
    __syncthreads();
    if (threadIdx.x == 0) {
        __hip_atomic_fetch_add(gctr, 1u, __ATOMIC_RELAXED, __HIP_MEMORY_SCOPE_WORKGROUP);
        const unsigned target = 32u * bi;
        while (__hip_atomic_load(gctr, __ATOMIC_RELAXED, __HIP_MEMORY_SCOPE_AGENT) < target)
            __builtin_amdgcn_s_sleep(1);
    }
    __syncthreads();
    asm volatile("buffer_inv sc0" ::: "memory");
}

__global__ void __launch_bounds__(512, 2)
rnn_main(const float* __restrict__ x, const float* __restrict__ whx,
         const _Float16* __restrict__ W, const float* __restrict__ bh,
         const float* __restrict__ wph, const float* __restrict__ bp,
         _Float16* __restrict__ h0, _Float16* __restrict__ h1,
         unsigned* __restrict__ ctr, float* __restrict__ out)
{
    // 128 KiB pinned W (cols [colbase, colbase+32)), fragment-major:
    //   slot(tile,kst,lane) = W[colbase+tile*16+(lane&15)][kst*32+(lane>>4)*8 ..+8]
    __shared__ uint4 ldsW[8192];
    // 2 x 8 KiB double-buffered A slice (k=128), fragment-major; slot index == tid:
    //   tid = [wm:1][ks:2][lane:6] -> h[rowbase+wm*16+(tid&15)][s*128+ks*32+((tid>>4)&3)*8 ..+8]
    __shared__ uint4 ldsA[2][512];
    __shared__ unsigned s_mslot;

    const int tid = threadIdx.x;

    // physical XCD id -> group; member slot via allocator (32 WGs/XCD: 1 WG/CU)
    int xcc;
    asm volatile("s_getreg_b32 %0, hwreg(HW_REG_XCC_ID)" : "=s"(xcc));
    const int g = xcc & 7;
    unsigned* gctr  = ctr + g * 64;
    unsigned* alloc = ctr + 512 + g * 64;
    if (tid == 0)
        s_mslot = __hip_atomic_fetch_add(alloc, 1u, __ATOMIC_RELAXED, __HIP_MEMORY_SCOPE_WORKGROUP);
    __syncthreads();
    const int m = (int)s_mslot;              // 0..31
    const int rowbase = g * 32;
    const int colbase = m * 64;

    const int lane = tid & 63;
    const int w    = tid >> 6;               // wave 0..7
    const int wm   = w & 1;                  // M-tile (rows wm*16..)
    const int wn   = w >> 1;                 // N-tile 0..3; wn<2: B in LDS, wn>=2: B reg/stream

    // ---- pin W cols [colbase, colbase+32) into LDS, fragment-major ----
    for (int s5 = tid; s5 < 8192; s5 += 512) {
        const int tile = s5 >> 12;
        const int kst  = (s5 >> 6) & 63;
        const int ln   = s5 & 63;
        const int col  = colbase + tile * 16 + (ln & 15);
        const int k0   = kst * 32 + (ln >> 4) * 8;
        ldsW[s5] = *(const uint4*)(W + (size_t)col * HID + k0);
    }

    // ---- step 0: h = tanh(x[:,0]*whx + bh) ----
    for (int i = tid; i < 32 * 64; i += 512) {
        const int r = i >> 6, c = i & 63;
        const int b = rowbase + r, j = colbase + c;
        h0[(size_t)b * HID + j] = (_Float16)fast_tanh(x[(size_t)b * SEQL] * whx[j] + bh[j]);
    }

    // per-thread A-staging source (one 16B fragment per slice, LDS slot == tid)
    const int srow  = rowbase + ((tid >> 8) & 1) * 16 + (tid & 15);
    const int skoff = ((tid >> 6) & 3) * 32 + ((tid >> 4) & 3) * 8;

    // per-wave constants
    const int cc = colbase + wn * 16 + (lane & 15);     // C/D col = lane&15
    const float wxc = whx[cc], bbc = bh[cc];
    const uint4* wb = &ldsW[wn * 4096 + lane];          // pinned-B base (wn<2)
    const _Float16* qb = W + (size_t)cc * HID + (lane >> 4) * 8;  // stream-B base (wn>=2)
    const int rb = rowbase + wm * 16 + (lane >> 4) * 4; // epilogue rows

    // streaming waves: pin K-half (kst 0..31) of B in 128 VGPRs for all 512 steps
    f16x8 Breg[32];
    if (wn >= 2) {
        #pragma unroll
        for (int i = 0; i < 32; ++i)
            Breg[i] = *(const f16x8*)(qb + i * 32);
    }

    group_barrier(gctr, 1u);

    for (int t = 1; t < SEQL; ++t) {
        const _Float16* hs = (t & 1) ? h0 : h1;
        _Float16*       hd = (t & 1) ? h1 : h0;
        const _Float16* sp = hs + (size_t)srow * HID + skoff;

        // keep the pinned-B fragments materialized (stop load sinking)
        if (wn >= 2) {
            #pragma unroll
            for (int i = 0; i < 32; ++i)
                asm volatile("" : "+v"(Breg[i]));
        }

        // prologue: stage A slice 0
        *(uintx4*)&ldsA[0][tid] = *(const uintx4*)sp;
        __syncthreads();

        f32x4 acc0 = {0.f,0.f,0.f,0.f}, acc1 = acc0;
        f16x8 Bf[2][8];   // streamed kst 32..63, double-buffered batches of 8

        #pragma unroll
        for (int s = 0; s < 16; ++s) {
            const int p = s & 1;
            uintx4 rA;
            if (s < 15)
                rA = *(const uintx4*)(sp + (s + 1) * 128);   // next A slice (T14 early-issue)
            if (wn >= 2 && (s == 6 || s == 8 || s == 10 || s == 12)) {
                const int q = (s - 6) >> 1;                  // batch q -> kst 32+8q..39+8q
                #pragma unroll
                for (int i = 0; i < 8; ++i)
                    Bf[q & 1][i] = *(const f16x8*)(qb + (32 + q * 8 + i) * 32);
            }
            #pragma unroll
            for (int ks = 0; ks < 4; ++ks) {
                const int kst = s * 4 + ks;
                const f16x8 a = *(const f16x8*)&ldsA[p][wm * 256 + ks * 64 + lane];
                f16x8 b;
                if (wn < 2)        b = *(const f16x8*)&wb[kst * 64];
                else if (kst < 32) b = Breg[kst];
                else               b = Bf[(kst >> 3) & 1][kst & 7];
                if (ks & 1) acc1 = __builtin_amdgcn_mfma_f32_16x16x32_f16(a, b, acc1, 0, 0, 0);
                else        acc0 = __builtin_amdgcn_mfma_f32_16x16x32_f16(a, b, acc0, 0, 0, 0);
            }
            if (s < 15)
                *(uintx4*)&ldsA[p ^ 1][tid] = rA;
            __syncthreads();
        }

        // epilogue: add x_t*whx + bh, tanh, store fp16
        const f32x4 ssum = acc0 + acc1;
        #pragma unroll
        for (int r = 0; r < 4; ++r) {
            const int br = rb + r;
            hd[(size_t)br * HID + cc] =
                (_Float16)fast_tanh(ssum[r] + x[(size_t)br * SEQL + t] * wxc + bbc);
        }

        group_barrier(gctr, (unsigned)(t + 1));
    }

    // ---- projection: p = h_last @ wph.T + bp (member m -> row rowbase+m) ----
    const int brow = rowbase + m;
    const _Float16* hp = h1 + (size_t)brow * HID + lane * 32;
    for (int c = w; c < NCLS; c += 8) {
        const float* wp = wph + (size_t)c * HID + lane * 32;
        float psum = 0.f;
        #pragma unroll
        for (int i = 0; i < 32; ++i) psum += (float)hp[i] * wp[i];
        #pragma unroll
        for (int off = 32; off >= 1; off >>= 1) psum += __shfl_xor(psum, off, 64);
        if (lane == 0) out[brow * NCLS + c] = psum + bp[c];
    }
}

extern "C" void kernel_launch(void* const* d_in, const int* in_sizes, int n_in,
                              void* d_out, int out_size, void* d_ws, size_t ws_size,
                              hipStream_t stream) {
    const float* x   = (const float*)d_in[0];
    const float* whx = (const float*)d_in[1];
    const float* whh = (const float*)d_in[2];
    const float* bh  = (const float*)d_in[3];
    const float* wph = (const float*)d_in[4];
    const float* bp  = (const float*)d_in[5];
    float* out = (float*)d_out;

    char* ws = (char*)d_ws;
    _Float16* W16 = (_Float16*)ws;                         // 8 MiB  whh fp16
    _Float16* h0  = (_Float16*)(ws + (size_t)(8u << 20));  // 1 MiB  h buffer A
    _Float16* h1  = (_Float16*)(ws + (size_t)(9u << 20));  // 1 MiB  h buffer B
    unsigned* ctr = (unsigned*)(ws + (size_t)(10u << 20)); // 4 KiB  counters

    hipMemsetAsync(ctr, 0, 2 * 8 * 64 * sizeof(unsigned), stream);
    convert_w_kernel<<<dim3(4096), dim3(256), 0, stream>>>(whh, W16);

    void* args[] = { (void*)&x, (void*)&whx, (void*)&W16, (void*)&bh, (void*)&wph,
                     (void*)&bp, (void*)&h0, (void*)&h1, (void*)&ctr, (void*)&out };
    hipLaunchCooperativeKernel((const void*)rnn_main, dim3(256), dim3(512),
                               args, 0, stream);
}